// Round 1
// baseline (702.549 us; speedup 1.0000x reference)
//
#include <hip/hip_runtime.h>
#include <math.h>

// FNO with global head, MI355X. Strategy: restricted sparse-mode DFT instead of FFT.
// All f32. Single in-place v buffer [16,16,256,256]; per layer:
//   f1: v -> Fw[b,c,h,ky]   (16 ky bins per row, per-thread rotator recurrence)
//   f2: Fw -> vft[b,c,kx,ky] (32 kx bins: 0..15 and 240..255)
//   mix: channel mixing with transposed spectral weights
//   i1: out_ft -> Gh[b,h,o,ky] (inverse over kx, scaled by c_ky/(H*W))
//   i2skip: Gh + skip GEMM + bias (+gelu) -> v (in place, LDS-staged)
// projection reduced: pooled(f) = W2 * pooled(gelu(W1 v + b1)) + b2  (pool q, not f)

#define TWO_PI_OVER_256 0.024543692606170259f

__device__ __forceinline__ float gelu_f(float x){
    // jax.nn.gelu approximate=True: 0.5x(1+tanh(z)) == x * sigmoid(2z)
    float x2 = x*x;
    float z2 = x*(1.5957691f + 0.07135482f*x2);   // 2*sqrt(2/pi)*(x + 0.044715 x^3)
    float e = __expf(-z2);
    return x / (1.0f + e);
}

__device__ __forceinline__ void build_tables(float* s_c, float* s_s){
    int t = threadIdx.x;
    if(t < 256){
        float ang = (float)t * TWO_PI_OVER_256;
        float sv, cv;
        sincosf(ang, &sv, &cv);
        s_c[t] = cv; s_s[t] = sv;
    }
}

__global__ __launch_bounds__(256) void fno_zero_k(float* __restrict__ p, int n){
    int i = blockIdx.x*256 + threadIdx.x;
    if(i < n) p[i] = 0.0f;
}

// Wt[l][kxIdx][ky][o][i] float2; kxIdx<16 -> w1[x=kxIdx]; else w2[x=kxIdx-16]
__global__ __launch_bounds__(256) void fno_wprep_k(const float* __restrict__ w1r, const float* __restrict__ w1i,
                                                   const float* __restrict__ w2r, const float* __restrict__ w2i,
                                                   float2* __restrict__ Wt){
    int lin = blockIdx.x;              // 4*32*16 = 2048 blocks
    int l  = lin >> 9;
    int rem = lin & 511;
    int kxIdx = rem >> 4;
    int ky = rem & 15;
    int t = threadIdx.x;
    int o = t >> 4, i = t & 15;
    int x = kxIdx & 15;
    const float* wr = (kxIdx < 16) ? w1r : w2r;
    const float* wi = (kxIdx < 16) ? w1i : w2i;
    int src = (((l*16 + i)*16 + o)*16 + x)*16 + ky;
    Wt[((l*32 + kxIdx)*16 + ky)*256 + o*16 + i] = make_float2(wr[src], wi[src]);
}

__global__ __launch_bounds__(256) void fno_lift_k(const float* __restrict__ x, const float* __restrict__ lw,
                                                  const float* __restrict__ lb, float* __restrict__ v){
    int b = blockIdx.x >> 8, h = blockIdx.x & 255;
    int w = threadIdx.x;
    float xv = x[(b*256 + h)*256 + w];
    #pragma unroll
    for(int c=0;c<16;c++){
        v[((b*16 + c)*256 + h)*256 + w] = lw[c]*xv + lb[c];
    }
}

// F1: Fw[bc][h][ky] = sum_w v[bc][h][w] e^{-2pi i ky w/256}, ky=0..15.
// grid 1024 = 256 bc * 4 row-blocks of 64 rows. thread: r = t&63 (row), kg = t>>6 (4 ky).
// Per 4-w chunk: accumulate accJ[q][j] += v[4m+j]*rot_q[m], rot stepped by e^{-2pi i 4ky/256};
// final combine with e^{-2pi i ky j/256}.
__global__ __launch_bounds__(256) void fno_f1_k(const float* __restrict__ v, float2* __restrict__ Fw){
    __shared__ float s_v[64*260];
    __shared__ float s_c[256], s_s[256];
    int t = threadIdx.x;
    build_tables(s_c, s_s);
    int bc = blockIdx.x >> 2;
    int h0 = (blockIdx.x & 3) * 64;
    const float* src = v + ((size_t)bc*256 + h0)*256;
    for(int i=t;i<16384;i+=256){
        int r = i >> 8, w = i & 255;
        s_v[r*260 + w] = src[r*256 + w];
    }
    __syncthreads();
    int r = t & 63, kg = t >> 6;
    float accR[4][4], accI[4][4], rc[4], rs[4], stc[4], sts[4];
    #pragma unroll
    for(int q=0;q<4;q++){
        int ky = kg*4+q;
        stc[q] = s_c[(4*ky)&255];
        sts[q] = s_s[(4*ky)&255];
        rc[q] = 1.0f; rs[q] = 0.0f;
        #pragma unroll
        for(int j=0;j<4;j++){ accR[q][j]=0.0f; accI[q][j]=0.0f; }
    }
    const float4* row = (const float4*)&s_v[r*260];
    #pragma unroll 4
    for(int m=0;m<64;m++){
        float4 v4 = row[m];
        #pragma unroll
        for(int q=0;q<4;q++){
            accR[q][0] += v4.x*rc[q]; accI[q][0] += v4.x*rs[q];
            accR[q][1] += v4.y*rc[q]; accI[q][1] += v4.y*rs[q];
            accR[q][2] += v4.z*rc[q]; accI[q][2] += v4.z*rs[q];
            accR[q][3] += v4.w*rc[q]; accI[q][3] += v4.w*rs[q];
            float nr = rc[q]*stc[q] + rs[q]*sts[q];
            float ni = rs[q]*stc[q] - rc[q]*sts[q];
            rc[q]=nr; rs[q]=ni;
        }
    }
    float2 outv[4];
    #pragma unroll
    for(int q=0;q<4;q++){
        int ky = kg*4+q;
        float oR=0.0f, oI=0.0f;
        #pragma unroll
        for(int j=0;j<4;j++){
            float cj = s_c[(ky*j)&255], sj = s_s[(ky*j)&255];
            oR += accR[q][j]*cj + accI[q][j]*sj;
            oI += accI[q][j]*cj - accR[q][j]*sj;
        }
        outv[q] = make_float2(oR, oI);
    }
    float2* dst = Fw + ((size_t)bc*256 + h0 + r)*16 + kg*4;
    *(float4*)&dst[0] = make_float4(outv[0].x,outv[0].y,outv[1].x,outv[1].y);
    *(float4*)&dst[2] = make_float4(outv[2].x,outv[2].y,outv[3].x,outv[3].y);
}

// F2: vft[bc][kxIdx][ky] = sum_h Fw[bc][h][ky] e^{-2pi i kx h/256}; kx = kxIdx or kxIdx+224.
// grid 256 (bc), 256 thr: hr = t>>6 (64-h range), kyp = (t>>3)&7 (ky pair), kxg = t&7 (4 kx).
__global__ __launch_bounds__(256) void fno_f2_k(const float2* __restrict__ Fw, float2* __restrict__ vft){
    __shared__ float2 s_fw[4096];      // 32KB, reused as reduction buffer
    __shared__ float s_c[256], s_s[256];
    int t = threadIdx.x;
    build_tables(s_c, s_s);
    int bc = blockIdx.x;
    {
        const float4* src = (const float4*)(Fw + (size_t)bc*4096);
        float4* d4 = (float4*)s_fw;
        for(int i=t;i<2048;i+=256) d4[i] = src[i];
    }
    __syncthreads();
    int hr = t>>6, kyp = (t>>3)&7, kxg = t&7;
    int h0 = hr*64;
    float rc[4], rs[4], stc[4], sts[4], aR[4][2], aI[4][2];
    #pragma unroll
    for(int p=0;p<4;p++){
        int kxIdx = kxg*4+p;
        int kx = kxIdx + ((kxIdx>=16)?224:0);
        int i0 = (kx*h0)&255;
        rc[p] = s_c[i0]; rs[p] = -s_s[i0];      // rot = e^{-i phi}
        stc[p] = s_c[kx]; sts[p] = s_s[kx];
        aR[p][0]=aR[p][1]=aI[p][0]=aI[p][1]=0.0f;
    }
    #pragma unroll 4
    for(int h=h0; h<h0+64; h++){
        float4 f = *(const float4*)&s_fw[h*16 + kyp*2];
        #pragma unroll
        for(int p=0;p<4;p++){
            aR[p][0] += f.x*rc[p] - f.y*rs[p];
            aI[p][0] += f.x*rs[p] + f.y*rc[p];
            aR[p][1] += f.z*rc[p] - f.w*rs[p];
            aI[p][1] += f.z*rs[p] + f.w*rc[p];
            float nr = rc[p]*stc[p] + rs[p]*sts[p];
            float ni = rs[p]*stc[p] - rc[p]*sts[p];
            rc[p]=nr; rs[p]=ni;
        }
    }
    __syncthreads();                   // done reading s_fw
    float2* s_red = s_fw;
    #pragma unroll
    for(int p=0;p<4;p++){
        #pragma unroll
        for(int y=0;y<2;y++){
            s_red[hr*512 + (kxg*4+p)*16 + kyp*2 + y] = make_float2(aR[p][y], aI[p][y]);
        }
    }
    __syncthreads();
    #pragma unroll
    for(int u=0;u<2;u++){
        int oidx = t*2 + u;
        float xr=0.0f, xi=0.0f;
        #pragma unroll
        for(int q=0;q<4;q++){ float2 pr = s_red[q*512 + oidx]; xr += pr.x; xi += pr.y; }
        vft[(size_t)bc*512 + oidx] = make_float2(xr, xi);
    }
}

// mix: out_ft[b][o][kxIdx][ky] = sum_i vft[b][i][kxIdx][ky] * Wt[l][kxIdx][ky][o][i]
__global__ __launch_bounds__(256) void fno_mix_k(const float2* __restrict__ vft, const float2* __restrict__ Wt,
                                                 float2* __restrict__ oft, int l){
    __shared__ float2 s_vf[256];
    int t = threadIdx.x;
    int b = blockIdx.x >> 5, kxIdx = blockIdx.x & 31;
    int hi = t >> 4, ky = t & 15;
    s_vf[hi*16 + ky] = vft[(size_t)(b*16 + hi)*512 + kxIdx*16 + ky];
    __syncthreads();
    int o = hi;
    const float2* wt = Wt + ((size_t)(l*32 + kxIdx)*16 + ky)*256 + o*16;
    float aR=0.0f, aI=0.0f;
    #pragma unroll
    for(int i=0;i<16;i++){
        float2 wv = wt[i];
        float2 vv = s_vf[i*16 + ky];
        aR += vv.x*wv.x - vv.y*wv.y;
        aI += vv.x*wv.y + vv.y*wv.x;
    }
    oft[(size_t)(b*16 + o)*512 + kxIdx*16 + ky] = make_float2(aR, aI);
}

// I1: Gh[b][h][o][ky] = s_ky * sum_kx oft[b][o][kx][ky] e^{+2pi i kx h/256}; s_ky = (ky?2:1)/65536
__global__ __launch_bounds__(256) void fno_i1_k(const float2* __restrict__ oft, float2* __restrict__ Gh){
    __shared__ float s_c[256], s_s[256];
    build_tables(s_c, s_s);
    __syncthreads();
    int b = blockIdx.x >> 4, o = blockIdx.x & 15;
    int h = threadIdx.x;
    const float2* row = oft + (size_t)(b*16 + o)*512;
    float hc = s_c[h], hs = s_s[h];
    float aR[16], aI[16];
    #pragma unroll
    for(int ky=0;ky<16;ky++){ aR[ky]=0.0f; aI[ky]=0.0f; }
    float rc = 1.0f, rs = 0.0f;        // e^{+i*0}
    for(int kxIdx=0;kxIdx<16;kxIdx++){
        #pragma unroll
        for(int ky=0;ky<16;ky++){
            float2 g = row[kxIdx*16 + ky];
            aR[ky] += g.x*rc - g.y*rs;
            aI[ky] += g.x*rs + g.y*rc;
        }
        float nr = rc*hc - rs*hs, ni = rc*hs + rs*hc;
        rc=nr; rs=ni;
    }
    { int i0 = (240*h)&255; rc = s_c[i0]; rs = s_s[i0]; }   // restart at kx=240
    for(int kxIdx=16;kxIdx<32;kxIdx++){
        #pragma unroll
        for(int ky=0;ky<16;ky++){
            float2 g = row[kxIdx*16 + ky];
            aR[ky] += g.x*rc - g.y*rs;
            aI[ky] += g.x*rs + g.y*rc;
        }
        float nr = rc*hc - rs*hs, ni = rc*hs + rs*hc;
        rc=nr; rs=ni;
    }
    const float inv = 1.0f/65536.0f;
    float2* dst = Gh + ((size_t)(b*256 + h)*16 + o)*16;
    float4 pack[8];
    #pragma unroll
    for(int ky=0;ky<16;ky+=2){
        float s0 = (ky==0) ? inv : 2.0f*inv;
        float s1 = 2.0f*inv;
        pack[ky/2] = make_float4(aR[ky]*s0, aI[ky]*s0, aR[ky+1]*s1, aI[ky+1]*s1);
    }
    float4* d4 = (float4*)dst;
    #pragma unroll
    for(int q=0;q<8;q++) d4[q] = pack[q];
}

// I2 + skip + bias (+gelu), in place on v. block = (b,h), thread = w.
__global__ __launch_bounds__(256) void fno_i2skip_k(const float2* __restrict__ Gh, float* __restrict__ v,
                                                    const float* __restrict__ skw, const float* __restrict__ skb,
                                                    int l, int do_gelu){
    __shared__ float s_vin[16*257];
    __shared__ float s_c[256], s_s[256];
    int t = threadIdx.x;
    build_tables(s_c, s_s);
    int b = blockIdx.x >> 8, h = blockIdx.x & 255;
    #pragma unroll
    for(int c=0;c<16;c++){
        s_vin[c*257 + t] = v[((size_t)(b*16 + c)*256 + h)*256 + t];
    }
    __syncthreads();
    int w = t;
    float vr[16];
    #pragma unroll
    for(int c=0;c<16;c++) vr[c] = s_vin[c*257 + w];
    float cw[16], sw[16];
    {
        int idx = 0;
        #pragma unroll
        for(int ky=0;ky<16;ky++){ cw[ky]=s_c[idx]; sw[ky]=s_s[idx]; idx = (idx + w)&255; }
    }
    const float2* gro = Gh + (size_t)(b*256 + h)*256;   // 256 float2 per (b,h)
    const float* swl = skw + l*256;
    const float* sbl = skb + l*16;
    for(int o=0;o<16;o++){
        float acc = sbl[o];
        const float2* g = gro + o*16;
        #pragma unroll
        for(int ky=0;ky<16;ky++){
            float2 gv = g[ky];
            acc += gv.x*cw[ky] - gv.y*sw[ky];
        }
        const float* swo = swl + o*16;
        #pragma unroll
        for(int c=0;c<16;c++) acc += swo[c]*vr[c];
        if(do_gelu) acc = gelu_f(acc);
        v[((size_t)(b*16 + o)*256 + h)*256 + w] = acc;
    }
}

// projection stage 1: poolq[b][k] += sum_pixels gelu(W1 v + b1). block (b,h); thread (ko=t&15, pg=t>>4).
__global__ __launch_bounds__(256) void fno_proj_k(const float* __restrict__ v, const float* __restrict__ W1,
                                                  const float* __restrict__ b1, float* __restrict__ poolq){
    __shared__ float4 s_v4[16*64];     // [c][64 slots] xor-swizzled
    __shared__ float4 s_w1[16*32];     // [c][32 k-quad slots] xor-swizzled
    __shared__ float s_red[16][132];
    int t = threadIdx.x;
    int b = blockIdx.x >> 8, h = blockIdx.x & 255;
    const float* src = v + ((size_t)(b*16)*256 + h)*256;
    for(int i=t;i<4096;i+=256){
        int c = i >> 8, w = i & 255;
        int slot = w >> 2;
        int sl = slot ^ ((slot>>3)&7);
        ((float*)s_v4)[(c*64 + sl)*4 + (w&3)] = src[(size_t)c*65536 + w];
    }
    for(int i=t;i<512;i+=256){
        int c = i >> 5, slot = i & 31;
        int sl = slot ^ ((slot>>3)&3);
        s_w1[c*32 + sl] = make_float4(W1[(slot*4+0)*16+c], W1[(slot*4+1)*16+c],
                                      W1[(slot*4+2)*16+c], W1[(slot*4+3)*16+c]);
    }
    __syncthreads();
    int ko = t & 15, pg = t >> 4;
    int sA = (ko*2) ^ (((ko*2)>>3)&3);
    int sB = (ko*2+1) ^ (((ko*2+1)>>3)&3);
    float bias[8];
    #pragma unroll
    for(int j=0;j<8;j++) bias[j] = b1[ko*8 + j];
    float acc[8];
    #pragma unroll
    for(int j=0;j<8;j++) acc[j] = 0.0f;
    for(int chunk=0;chunk<4;chunk++){
        int p4 = pg*4 + chunk;
        int p4s = p4 ^ ((p4>>3)&7);
        float u[4][8];
        #pragma unroll
        for(int pix=0;pix<4;pix++)
            #pragma unroll
            for(int j=0;j<8;j++) u[pix][j] = bias[j];
        #pragma unroll 4
        for(int c=0;c<16;c++){
            float4 vv = s_v4[c*64 + p4s];
            float4 wA = s_w1[c*32 + sA];
            float4 wB = s_w1[c*32 + sB];
            float vx[4] = {vv.x, vv.y, vv.z, vv.w};
            #pragma unroll
            for(int pix=0;pix<4;pix++){
                u[pix][0] += vx[pix]*wA.x; u[pix][1] += vx[pix]*wA.y;
                u[pix][2] += vx[pix]*wA.z; u[pix][3] += vx[pix]*wA.w;
                u[pix][4] += vx[pix]*wB.x; u[pix][5] += vx[pix]*wB.y;
                u[pix][6] += vx[pix]*wB.z; u[pix][7] += vx[pix]*wB.w;
            }
        }
        #pragma unroll
        for(int pix=0;pix<4;pix++)
            #pragma unroll
            for(int j=0;j<8;j++) acc[j] += gelu_f(u[pix][j]);
    }
    #pragma unroll
    for(int j=0;j<8;j++) s_red[pg][ko*8 + j] = acc[j];
    __syncthreads();
    if(t < 128){
        float sum = 0.0f;
        #pragma unroll
        for(int pg2=0;pg2<16;pg2++) sum += s_red[pg2][t];
        atomicAdd(&poolq[b*128 + t], sum);
    }
}

// head: pooled = W2 * (poolq/65536) + b2 ; out = tanh(pooled @ head_w^T + head_b)
__global__ __launch_bounds__(1024) void fno_head_k(const float* __restrict__ poolq, const float* __restrict__ W2,
                                                   const float* __restrict__ b2, const float* __restrict__ hw,
                                                   const float* __restrict__ hb, float* __restrict__ out){
    __shared__ float s_pool[16][68];
    int t = threadIdx.x;
    int b = t >> 6, j = t & 63;
    const float* pq = poolq + b*128;
    const float* w2 = W2 + j*128;
    float dot = 0.0f;
    for(int k=0;k<128;k++) dot += w2[k]*pq[k];
    s_pool[b][j] = b2[j] + dot*(1.0f/65536.0f);
    __syncthreads();
    if(t < 32){
        int bb = t >> 1, c2 = t & 1;
        float z = hb[c2];
        #pragma unroll
        for(int j2=0;j2<64;j2++) z += hw[c2*64 + j2]*s_pool[bb][j2];
        out[bb*2 + c2] = tanhf(z);
    }
}

extern "C" void kernel_launch(void* const* d_in, const int* in_sizes, int n_in,
                              void* d_out, int out_size, void* d_ws, size_t ws_size,
                              hipStream_t stream) {
    const float* x       = (const float*)d_in[0];
    const float* lift_w  = (const float*)d_in[1];
    const float* lift_b  = (const float*)d_in[2];
    const float* w1r     = (const float*)d_in[3];
    const float* w1i     = (const float*)d_in[4];
    const float* w2r     = (const float*)d_in[5];
    const float* w2i     = (const float*)d_in[6];
    const float* skip_w  = (const float*)d_in[7];
    const float* skip_b  = (const float*)d_in[8];
    const float* proj_w1 = (const float*)d_in[9];
    const float* proj_b1 = (const float*)d_in[10];
    const float* proj_w2 = (const float*)d_in[11];
    const float* proj_b2 = (const float*)d_in[12];
    const float* head_w  = (const float*)d_in[13];
    const float* head_b  = (const float*)d_in[14];
    float* out = (float*)d_out;

    float*  v    = (float*)d_ws;                 // 16,777,216 floats (in-place across layers)
    float2* Fw   = (float2*)(v + 16777216);      // 1,048,576 float2
    float2* vft  = Fw  + 1048576;                // 131,072
    float2* oft  = vft + 131072;                 // 131,072
    float2* Gh   = oft + 131072;                 // 1,048,576
    float2* Wt   = Gh  + 1048576;                // 524,288
    float*  poolq = (float*)(Wt + 524288);       // 2,048 floats  (total ~90.2 MB)

    fno_zero_k<<<8, 256, 0, stream>>>(poolq, 2048);
    fno_wprep_k<<<2048, 256, 0, stream>>>(w1r, w1i, w2r, w2i, Wt);
    fno_lift_k<<<4096, 256, 0, stream>>>(x, lift_w, lift_b, v);

    for(int l=0; l<4; l++){
        fno_f1_k<<<1024, 256, 0, stream>>>(v, Fw);
        fno_f2_k<<<256, 256, 0, stream>>>(Fw, vft);
        fno_mix_k<<<512, 256, 0, stream>>>(vft, Wt, oft, l);
        fno_i1_k<<<256, 256, 0, stream>>>(oft, Gh);
        fno_i2skip_k<<<4096, 256, 0, stream>>>(Gh, v, skip_w, skip_b, l, (l<3)?1:0);
    }

    fno_proj_k<<<4096, 256, 0, stream>>>(v, proj_w1, proj_b1, poolq);
    fno_head_k<<<1, 1024, 0, stream>>>(poolq, proj_w2, proj_b2, head_w, head_b, out);
}

// Round 2
// 678.192 us; speedup vs baseline: 1.0359x; 1.0359x over previous
//
#include <hip/hip_runtime.h>
#include <math.h>

// FNO with global head, MI355X. Round 2: fused restricted-mode DFT pipeline.
// Kernels:
//   liftf1 : x -> v (HBM) and Fw[b,c,h,ky] (row DFT fused with lift)
//   f2     : Fw -> vft[b,c,kx,ky] (column DFT, 32 kx bins)
//   mixi1  : vft -> (channel mix in LDS) -> Gh[b,h,o,ky] (inverse over kx)
//   i2f1   : Gh + skip + bias (+gelu) -> v, and (for l<3) fused row DFT -> Fw
//   proj2  : v -> poolq (W1 GEMM with SGPR weights, gelu, two-phase pooled reduce)
//   head   : poolq -> out

#define TWO_PI_OVER_256 0.024543692606170259f

__device__ __forceinline__ float gelu_f(float x){
    // jax.nn.gelu approximate=True: 0.5x(1+tanh(z)) == x * sigmoid(2z)
    float x2 = x*x;
    float z2 = x*(1.5957691f + 0.07135482f*x2);   // 2*sqrt(2/pi)*(x + 0.044715 x^3)
    float e = __expf(-z2);
    return x / (1.0f + e);
}

__device__ __forceinline__ void build_tables(float* s_c, float* s_s){
    int t = threadIdx.x;
    if(t < 256){
        float ang = (float)t * TWO_PI_OVER_256;
        float sv, cv;
        sincosf(ang, &sv, &cv);
        s_c[t] = cv; s_s[t] = sv;
    }
}

// Row DFT: F(ky) = sum_w row[w] e^{-2pi i ky w/256}, j-split over w%4, rotator over w/4.
__device__ __forceinline__ float2 dft_row(const float* s_row, const float* s_c, const float* s_s, int ky){
    float stc = s_c[(4*ky)&255], sts = s_s[(4*ky)&255];
    float rc = 1.0f, rs = 0.0f;
    float accR[4] = {0,0,0,0}, accI[4] = {0,0,0,0};
    const float4* row4 = (const float4*)s_row;
    #pragma unroll 4
    for(int m=0;m<64;m++){
        float4 v4 = row4[m];
        accR[0]+=v4.x*rc; accI[0]+=v4.x*rs;
        accR[1]+=v4.y*rc; accI[1]+=v4.y*rs;
        accR[2]+=v4.z*rc; accI[2]+=v4.z*rs;
        accR[3]+=v4.w*rc; accI[3]+=v4.w*rs;
        float nr = rc*stc + rs*sts;
        float ni = rs*stc - rc*sts;
        rc=nr; rs=ni;
    }
    float oR=0.0f, oI=0.0f;
    #pragma unroll
    for(int j=0;j<4;j++){
        float cj = s_c[(ky*j)&255], sj = s_s[(ky*j)&255];
        oR += accR[j]*cj + accI[j]*sj;
        oI += accI[j]*cj - accR[j]*sj;
    }
    return make_float2(oR, oI);
}

__global__ __launch_bounds__(256) void fno_zero_k(float* __restrict__ p, int n){
    int i = blockIdx.x*256 + threadIdx.x;
    if(i < n) p[i] = 0.0f;
}

// Wt2[l][o][m=kx*16+ky][i] float2; kxIdx<16 -> w1[x=kxIdx]; else w2[x=kxIdx-16]
__global__ __launch_bounds__(256) void fno_wprep_k(const float* __restrict__ w1r, const float* __restrict__ w1i,
                                                   const float* __restrict__ w2r, const float* __restrict__ w2i,
                                                   float2* __restrict__ Wt2){
    int lin = blockIdx.x;              // 4*16*32 = 2048 blocks: (l,o,kxIdx)
    int l  = lin >> 9;
    int rem = lin & 511;
    int o = rem >> 5;
    int kxIdx = rem & 31;
    int t = threadIdx.x;
    int ky = t >> 4, i = t & 15;
    int x = kxIdx & 15;
    const float* wr = (kxIdx < 16) ? w1r : w2r;
    const float* wi = (kxIdx < 16) ? w1i : w2i;
    int src = (((l*16 + i)*16 + o)*16 + x)*16 + ky;
    Wt2[((size_t)(l*16 + o)*512 + kxIdx*16 + ky)*16 + i] = make_float2(wr[src], wi[src]);
}

// lift + row DFT. grid 4096 (b,h), 256 thr.
__global__ __launch_bounds__(256) void fno_liftf1_k(const float* __restrict__ x, const float* __restrict__ lw,
                                                    const float* __restrict__ lb, float* __restrict__ v,
                                                    float2* __restrict__ Fw){
    __shared__ float s_v[16*260];
    __shared__ float s_c[256], s_s[256];
    int t = threadIdx.x;
    build_tables(s_c, s_s);
    int b = blockIdx.x >> 8, h = blockIdx.x & 255;
    float xv = x[(b*256 + h)*256 + t];
    #pragma unroll
    for(int c=0;c<16;c++){
        float val = lw[c]*xv + lb[c];
        v[((size_t)(b*16 + c)*256 + h)*256 + t] = val;
        s_v[c*260 + t] = val;
    }
    __syncthreads();
    int c = t >> 4, ky = t & 15;
    float2 r = dft_row(s_v + c*260, s_c, s_s, ky);
    Fw[((size_t)(b*16 + c)*256 + h)*16 + ky] = r;
}

// F2: vft[bc][kxIdx][ky] = sum_h Fw[bc][h][ky] e^{-2pi i kx h/256}; kx = kxIdx or kxIdx+224.
__global__ __launch_bounds__(256) void fno_f2_k(const float2* __restrict__ Fw, float2* __restrict__ vft){
    __shared__ float2 s_fw[4096];      // 32KB, reused as reduction buffer
    __shared__ float s_c[256], s_s[256];
    int t = threadIdx.x;
    build_tables(s_c, s_s);
    int bc = blockIdx.x;
    {
        const float4* src = (const float4*)(Fw + (size_t)bc*4096);
        float4* d4 = (float4*)s_fw;
        for(int i=t;i<2048;i+=256) d4[i] = src[i];
    }
    __syncthreads();
    int hr = t>>6, kyp = (t>>3)&7, kxg = t&7;
    int h0 = hr*64;
    float rc[4], rs[4], stc[4], sts[4], aR[4][2], aI[4][2];
    #pragma unroll
    for(int p=0;p<4;p++){
        int kxIdx = kxg*4+p;
        int kx = kxIdx + ((kxIdx>=16)?224:0);
        int i0 = (kx*h0)&255;
        rc[p] = s_c[i0]; rs[p] = -s_s[i0];      // rot = e^{-i phi}
        stc[p] = s_c[kx]; sts[p] = s_s[kx];
        aR[p][0]=aR[p][1]=aI[p][0]=aI[p][1]=0.0f;
    }
    #pragma unroll 4
    for(int h=h0; h<h0+64; h++){
        float4 f = *(const float4*)&s_fw[h*16 + kyp*2];
        #pragma unroll
        for(int p=0;p<4;p++){
            aR[p][0] += f.x*rc[p] - f.y*rs[p];
            aI[p][0] += f.x*rs[p] + f.y*rc[p];
            aR[p][1] += f.z*rc[p] - f.w*rs[p];
            aI[p][1] += f.z*rs[p] + f.w*rc[p];
            float nr = rc[p]*stc[p] + rs[p]*sts[p];
            float ni = rs[p]*stc[p] - rc[p]*sts[p];
            rc[p]=nr; rs[p]=ni;
        }
    }
    __syncthreads();                   // done reading s_fw
    float2* s_red = s_fw;
    #pragma unroll
    for(int p=0;p<4;p++){
        #pragma unroll
        for(int y=0;y<2;y++){
            s_red[hr*512 + (kxg*4+p)*16 + kyp*2 + y] = make_float2(aR[p][y], aI[p][y]);
        }
    }
    __syncthreads();
    #pragma unroll
    for(int u=0;u<2;u++){
        int oidx = t*2 + u;
        float xr=0.0f, xi=0.0f;
        #pragma unroll
        for(int q=0;q<4;q++){ float2 pr = s_red[q*512 + oidx]; xr += pr.x; xi += pr.y; }
        vft[(size_t)bc*512 + oidx] = make_float2(xr, xi);
    }
}

// mix + I1 fused. grid (b,o)=256 blocks, 256 thr.
// mix: s_oft[m] = sum_i vft[b][i][m] * Wt2[l][o][m][i]  (thread handles modes t, t+256)
// i1:  Gh[b][h][o][ky] = s_ky * sum_kx s_oft[kx*16+ky] e^{+2pi i kx h/256}
__global__ __launch_bounds__(256) void fno_mixi1_k(const float2* __restrict__ vft, const float2* __restrict__ Wt2,
                                                   float2* __restrict__ Gh, int l){
    __shared__ float2 s_oft[512];
    __shared__ float s_c[256], s_s[256];
    int t = threadIdx.x;
    build_tables(s_c, s_s);
    int b = blockIdx.x >> 4, o = blockIdx.x & 15;
    const float2* vb = vft + (size_t)b*8192;
    const float2* wb = Wt2 + (size_t)(l*16 + o)*512*16;
    #pragma unroll
    for(int u=0;u<2;u++){
        int m = t + u*256;
        const float2* wm = wb + m*16;
        float aR=0.0f, aI=0.0f;
        #pragma unroll
        for(int i=0;i<16;i++){
            float2 vv = vb[i*512 + m];
            float2 wv = wm[i];
            aR += vv.x*wv.x - vv.y*wv.y;
            aI += vv.x*wv.y + vv.y*wv.x;
        }
        s_oft[m] = make_float2(aR, aI);
    }
    __syncthreads();
    int h = t;
    float hc = s_c[h], hs = s_s[h];
    float aR[16], aI[16];
    #pragma unroll
    for(int ky=0;ky<16;ky++){ aR[ky]=0.0f; aI[ky]=0.0f; }
    float rc = 1.0f, rs = 0.0f;        // e^{+i*0}
    for(int kxIdx=0;kxIdx<16;kxIdx++){
        #pragma unroll
        for(int ky=0;ky<16;ky++){
            float2 g = s_oft[kxIdx*16 + ky];
            aR[ky] += g.x*rc - g.y*rs;
            aI[ky] += g.x*rs + g.y*rc;
        }
        float nr = rc*hc - rs*hs, ni = rc*hs + rs*hc;
        rc=nr; rs=ni;
    }
    { int i0 = (240*h)&255; rc = s_c[i0]; rs = s_s[i0]; }   // restart at kx=240
    for(int kxIdx=16;kxIdx<32;kxIdx++){
        #pragma unroll
        for(int ky=0;ky<16;ky++){
            float2 g = s_oft[kxIdx*16 + ky];
            aR[ky] += g.x*rc - g.y*rs;
            aI[ky] += g.x*rs + g.y*rc;
        }
        float nr = rc*hc - rs*hs, ni = rc*hs + rs*hc;
        rc=nr; rs=ni;
    }
    const float inv = 1.0f/65536.0f;
    float4 pack[8];
    #pragma unroll
    for(int ky=0;ky<16;ky+=2){
        float s0 = (ky==0) ? inv : 2.0f*inv;
        float s1 = 2.0f*inv;
        pack[ky/2] = make_float4(aR[ky]*s0, aI[ky]*s0, aR[ky+1]*s1, aI[ky+1]*s1);
    }
    float4* d4 = (float4*)(Gh + ((size_t)(b*256 + h)*16 + o)*16);
    #pragma unroll
    for(int q=0;q<8;q++) d4[q] = pack[q];
}

// I2 + skip + bias (+gelu), in place on v; optional fused row DFT -> Fw.
// grid 4096 (b,h), 256 thr.
__global__ __launch_bounds__(256) void fno_i2f1_k(const float2* __restrict__ Gh, float* __restrict__ v,
                                                  const float* __restrict__ skw, const float* __restrict__ skb,
                                                  float2* __restrict__ Fw, int l, int do_gelu, int do_f1){
    __shared__ float s_v[16*260];
    __shared__ float2 s_g[256];
    __shared__ float s_c[256], s_s[256];
    int t = threadIdx.x;
    build_tables(s_c, s_s);
    int b = blockIdx.x >> 8, h = blockIdx.x & 255;
    #pragma unroll
    for(int c=0;c<16;c++) s_v[c*260 + t] = v[((size_t)(b*16 + c)*256 + h)*256 + t];
    if(t < 128) ((float4*)s_g)[t] = ((const float4*)(Gh + (size_t)(b*256 + h)*256))[t];
    __syncthreads();
    float vr[16];
    #pragma unroll
    for(int c=0;c<16;c++) vr[c] = s_v[c*260 + t];
    float cw[16], sw[16];
    {
        int idx = 0;
        #pragma unroll
        for(int ky=0;ky<16;ky++){ cw[ky]=s_c[idx]; sw[ky]=s_s[idx]; idx = (idx + t)&255; }
    }
    const float* swl = skw + l*256;
    const float* sbl = skb + l*16;
    float outv[16];
    for(int o=0;o<16;o++){
        float acc = sbl[o];
        #pragma unroll
        for(int ky=0;ky<16;ky++){
            float2 gv = s_g[o*16 + ky];
            acc += gv.x*cw[ky] - gv.y*sw[ky];
        }
        const float* swo = swl + o*16;
        #pragma unroll
        for(int c=0;c<16;c++) acc += swo[c]*vr[c];
        if(do_gelu) acc = gelu_f(acc);
        outv[o] = acc;
    }
    __syncthreads();   // everyone done reading s_v columns before in-place overwrite
    #pragma unroll
    for(int o=0;o<16;o++){
        v[((size_t)(b*16 + o)*256 + h)*256 + t] = outv[o];
        s_v[o*260 + t] = outv[o];
    }
    if(do_f1){
        __syncthreads();
        int c = t >> 4, ky = t & 15;
        float2 r = dft_row(s_v + c*260, s_c, s_s, ky);
        Fw[((size_t)(b*16 + c)*256 + h)*16 + ky] = r;
    }
}

// projection stage 1: poolq[b][k] += sum_pixels gelu(b1 + W1 v).
// thread = pixel; v in 16 regs; weights via wave-uniform scalar loads; q -> LDS in 32-k chunks.
__global__ __launch_bounds__(256) void fno_proj2_k(const float* __restrict__ v, const float* __restrict__ W1,
                                                   const float* __restrict__ b1, float* __restrict__ poolq){
    __shared__ float4 s_q[256*9];      // 36 KB (also reused for final reduce: 32*33+32 < 2304)
    int t = threadIdx.x;
    int b = blockIdx.x >> 8, h = blockIdx.x & 255;
    float vr[16];
    #pragma unroll
    for(int c=0;c<16;c++) vr[c] = v[((size_t)(b*16 + c)*256 + h)*256 + t];
    int g8 = t & 7, pr = t >> 3;
    float4 acc[4];
    #pragma unroll
    for(int ch=0;ch<4;ch++) acc[ch] = make_float4(0,0,0,0);
    for(int ch=0; ch<4; ch++){
        for(int kg=0; kg<8; kg++){
            int kb = ch*32 + kg*4;                 // uniform -> scalar loads
            const float* w0 = W1 + kb*16;
            float u0 = b1[kb], u1 = b1[kb+1], u2 = b1[kb+2], u3 = b1[kb+3];
            #pragma unroll
            for(int c=0;c<16;c++){
                float vv = vr[c];
                u0 += vv*w0[c];
                u1 += vv*w0[16+c];
                u2 += vv*w0[32+c];
                u3 += vv*w0[48+c];
            }
            s_q[t*9 + kg] = make_float4(gelu_f(u0), gelu_f(u1), gelu_f(u2), gelu_f(u3));
        }
        __syncthreads();
        #pragma unroll
        for(int pp=0;pp<8;pp++){
            float4 f = s_q[(pr*8 + pp)*9 + g8];
            acc[ch].x += f.x; acc[ch].y += f.y; acc[ch].z += f.z; acc[ch].w += f.w;
        }
        __syncthreads();
    }
    #pragma unroll
    for(int ch=0;ch<4;ch++) s_q[(ch*8 + g8)*33 + pr] = acc[ch];
    __syncthreads();
    if(t < 32){
        float4 a = make_float4(0,0,0,0);
        for(int pr2=0;pr2<32;pr2++){
            float4 f = s_q[t*33 + pr2];
            a.x += f.x; a.y += f.y; a.z += f.z; a.w += f.w;
        }
        int kbase = (t>>3)*32 + (t&7)*4;
        atomicAdd(&poolq[b*128 + kbase + 0], a.x);
        atomicAdd(&poolq[b*128 + kbase + 1], a.y);
        atomicAdd(&poolq[b*128 + kbase + 2], a.z);
        atomicAdd(&poolq[b*128 + kbase + 3], a.w);
    }
}

// head: pooled = W2 * (poolq/65536) + b2 ; out = tanh(pooled @ head_w^T + head_b)
__global__ __launch_bounds__(1024) void fno_head_k(const float* __restrict__ poolq, const float* __restrict__ W2,
                                                   const float* __restrict__ b2, const float* __restrict__ hw,
                                                   const float* __restrict__ hb, float* __restrict__ out){
    __shared__ float s_pool[16][68];
    int t = threadIdx.x;
    int b = t >> 6, j = t & 63;
    const float* pq = poolq + b*128;
    const float* w2 = W2 + j*128;
    float dot = 0.0f;
    for(int k=0;k<128;k++) dot += w2[k]*pq[k];
    s_pool[b][j] = b2[j] + dot*(1.0f/65536.0f);
    __syncthreads();
    if(t < 32){
        int bb = t >> 1, c2 = t & 1;
        float z = hb[c2];
        #pragma unroll
        for(int j2=0;j2<64;j2++) z += hw[c2*64 + j2]*s_pool[bb][j2];
        out[bb*2 + c2] = tanhf(z);
    }
}

extern "C" void kernel_launch(void* const* d_in, const int* in_sizes, int n_in,
                              void* d_out, int out_size, void* d_ws, size_t ws_size,
                              hipStream_t stream) {
    const float* x       = (const float*)d_in[0];
    const float* lift_w  = (const float*)d_in[1];
    const float* lift_b  = (const float*)d_in[2];
    const float* w1r     = (const float*)d_in[3];
    const float* w1i     = (const float*)d_in[4];
    const float* w2r     = (const float*)d_in[5];
    const float* w2i     = (const float*)d_in[6];
    const float* skip_w  = (const float*)d_in[7];
    const float* skip_b  = (const float*)d_in[8];
    const float* proj_w1 = (const float*)d_in[9];
    const float* proj_b1 = (const float*)d_in[10];
    const float* proj_w2 = (const float*)d_in[11];
    const float* proj_b2 = (const float*)d_in[12];
    const float* head_w  = (const float*)d_in[13];
    const float* head_b  = (const float*)d_in[14];
    float* out = (float*)d_out;

    float*  v    = (float*)d_ws;                 // 16,777,216 floats
    float2* Fw   = (float2*)(v + 16777216);      // 1,048,576 float2
    float2* vft  = Fw  + 1048576;                // 131,072
    float2* Gh   = vft + 131072;                 // 1,048,576
    float2* Wt2  = Gh  + 1048576;                // 524,288
    float*  poolq = (float*)(Wt2 + 524288);      // 2,048 floats (total ~85 MB)

    fno_zero_k<<<8, 256, 0, stream>>>(poolq, 2048);
    fno_wprep_k<<<2048, 256, 0, stream>>>(w1r, w1i, w2r, w2i, Wt2);
    fno_liftf1_k<<<4096, 256, 0, stream>>>(x, lift_w, lift_b, v, Fw);

    for(int l=0; l<4; l++){
        fno_f2_k<<<256, 256, 0, stream>>>(Fw, vft);
        fno_mixi1_k<<<256, 256, 0, stream>>>(vft, Wt2, Gh, l);
        fno_i2f1_k<<<4096, 256, 0, stream>>>(Gh, v, skip_w, skip_b, Fw, l,
                                             (l<3)?1:0, (l<3)?1:0);
    }

    fno_proj2_k<<<4096, 256, 0, stream>>>(v, proj_w1, proj_b1, poolq);
    fno_head_k<<<1, 1024, 0, stream>>>(poolq, proj_w2, proj_b2, head_w, head_b, out);
}

// Round 3
// 663.249 us; speedup vs baseline: 1.0593x; 1.0225x over previous
//
#include <hip/hip_runtime.h>
#include <math.h>

// FNO with global head, MI355X. Round 3.
//   liftf1 : x -> v and Fw (row DFT fused with lift)
//   f2q    : Fw -> vftp[bc][q][512] (column DFT, quarter h-ranges, 1024 blocks)
//   mixi1  : vftp (sum 4 partials) -> channel mix in LDS -> Gh
//   i2f1   : Gh + skip + bias (+gelu) -> v, fused row DFT -> Fw (l<3)
//   proj3  : v -> poolq ; W1+b1 in LDS (b128 broadcasts), 2 px/thread, fast gelu
//   head   : poolq -> out

#define TWO_PI_OVER_256 0.024543692606170259f

__device__ __forceinline__ float gelu_f(float x){
    // jax.nn.gelu approximate=True: 0.5x(1+tanh(z)) == x * sigmoid(2z)
    float x2 = x*x;
    float z2 = x*(1.5957691f + 0.07135482f*x2);   // 2*sqrt(2/pi)*(x + 0.044715 x^3)
    float e = __expf(-z2);
    return x * __builtin_amdgcn_rcpf(1.0f + e);   // v_rcp instead of precise div
}

__device__ __forceinline__ void build_tables(float* s_c, float* s_s){
    int t = threadIdx.x;
    if(t < 256){
        float ang = (float)t * TWO_PI_OVER_256;
        float sv, cv;
        sincosf(ang, &sv, &cv);
        s_c[t] = cv; s_s[t] = sv;
    }
}

// Row DFT: F(ky) = sum_w row[w] e^{-2pi i ky w/256}, j-split over w%4, rotator over w/4.
__device__ __forceinline__ float2 dft_row(const float* s_row, const float* s_c, const float* s_s, int ky){
    float stc = s_c[(4*ky)&255], sts = s_s[(4*ky)&255];
    float rc = 1.0f, rs = 0.0f;
    float accR[4] = {0,0,0,0}, accI[4] = {0,0,0,0};
    const float4* row4 = (const float4*)s_row;
    #pragma unroll 4
    for(int m=0;m<64;m++){
        float4 v4 = row4[m];
        accR[0]+=v4.x*rc; accI[0]+=v4.x*rs;
        accR[1]+=v4.y*rc; accI[1]+=v4.y*rs;
        accR[2]+=v4.z*rc; accI[2]+=v4.z*rs;
        accR[3]+=v4.w*rc; accI[3]+=v4.w*rs;
        float nr = rc*stc + rs*sts;
        float ni = rs*stc - rc*sts;
        rc=nr; rs=ni;
    }
    float oR=0.0f, oI=0.0f;
    #pragma unroll
    for(int j=0;j<4;j++){
        float cj = s_c[(ky*j)&255], sj = s_s[(ky*j)&255];
        oR += accR[j]*cj + accI[j]*sj;
        oI += accI[j]*cj - accR[j]*sj;
    }
    return make_float2(oR, oI);
}

__global__ __launch_bounds__(256) void fno_zero_k(float* __restrict__ p, int n){
    int i = blockIdx.x*256 + threadIdx.x;
    if(i < n) p[i] = 0.0f;
}

// Wt2[l][o][m=kx*16+ky][i] float2
__global__ __launch_bounds__(256) void fno_wprep_k(const float* __restrict__ w1r, const float* __restrict__ w1i,
                                                   const float* __restrict__ w2r, const float* __restrict__ w2i,
                                                   float2* __restrict__ Wt2){
    int lin = blockIdx.x;              // 4*16*32 = 2048 blocks: (l,o,kxIdx)
    int l  = lin >> 9;
    int rem = lin & 511;
    int o = rem >> 5;
    int kxIdx = rem & 31;
    int t = threadIdx.x;
    int ky = t >> 4, i = t & 15;
    int x = kxIdx & 15;
    const float* wr = (kxIdx < 16) ? w1r : w2r;
    const float* wi = (kxIdx < 16) ? w1i : w2i;
    int src = (((l*16 + i)*16 + o)*16 + x)*16 + ky;
    Wt2[((size_t)(l*16 + o)*512 + kxIdx*16 + ky)*16 + i] = make_float2(wr[src], wi[src]);
}

// lift + row DFT. grid 4096 (b,h), 256 thr.
__global__ __launch_bounds__(256) void fno_liftf1_k(const float* __restrict__ x, const float* __restrict__ lw,
                                                    const float* __restrict__ lb, float* __restrict__ v,
                                                    float2* __restrict__ Fw){
    __shared__ float s_v[16*260];
    __shared__ float s_c[256], s_s[256];
    int t = threadIdx.x;
    build_tables(s_c, s_s);
    int b = blockIdx.x >> 8, h = blockIdx.x & 255;
    float xv = x[(b*256 + h)*256 + t];
    #pragma unroll
    for(int c=0;c<16;c++){
        float val = lw[c]*xv + lb[c];
        v[((size_t)(b*16 + c)*256 + h)*256 + t] = val;
        s_v[c*260 + t] = val;
    }
    __syncthreads();
    int c = t >> 4, ky = t & 15;
    float2 r = dft_row(s_v + c*260, s_c, s_s, ky);
    Fw[((size_t)(b*16 + c)*256 + h)*16 + ky] = r;
}

// F2 quarter-split: vftp[(bc*4+qr)][oidx] = sum_{h in quarter} Fw[bc][h][ky] e^{-2pi i kx h/256}
// grid 1024 = (bc, qr). thread: sub = t>>6 (16-h subrange), kyp=(t>>3)&7, kxg=t&7.
__global__ __launch_bounds__(256) void fno_f2q_k(const float2* __restrict__ Fw, float2* __restrict__ vftp){
    __shared__ float2 s_fw[1024];      // 64 h x 16 ky
    __shared__ float2 s_red[2048];
    __shared__ float s_c[256], s_s[256];
    int t = threadIdx.x;
    build_tables(s_c, s_s);
    int bc = blockIdx.x >> 2, qr = blockIdx.x & 3;
    int qh = qr*64;
    {
        const float4* src = (const float4*)(Fw + (size_t)bc*4096 + qh*16);
        float4* d4 = (float4*)s_fw;
        for(int i=t;i<512;i+=256) d4[i] = src[i];
    }
    __syncthreads();
    int sub = t>>6, kyp = (t>>3)&7, kxg = t&7;
    int h0 = qh + sub*16;
    float rc[4], rs[4], stc[4], sts[4], aR[4][2], aI[4][2];
    #pragma unroll
    for(int p=0;p<4;p++){
        int kxIdx = kxg*4+p;
        int kx = kxIdx + ((kxIdx>=16)?224:0);
        int i0 = (kx*h0)&255;
        rc[p] = s_c[i0]; rs[p] = -s_s[i0];      // rot = e^{-i phi}
        stc[p] = s_c[kx]; sts[p] = s_s[kx];
        aR[p][0]=aR[p][1]=aI[p][0]=aI[p][1]=0.0f;
    }
    #pragma unroll 4
    for(int hh=0; hh<16; hh++){
        float4 f = *(const float4*)&s_fw[(sub*16 + hh)*16 + kyp*2];
        #pragma unroll
        for(int p=0;p<4;p++){
            aR[p][0] += f.x*rc[p] - f.y*rs[p];
            aI[p][0] += f.x*rs[p] + f.y*rc[p];
            aR[p][1] += f.z*rc[p] - f.w*rs[p];
            aI[p][1] += f.z*rs[p] + f.w*rc[p];
            float nr = rc[p]*stc[p] + rs[p]*sts[p];
            float ni = rs[p]*stc[p] - rc[p]*sts[p];
            rc[p]=nr; rs[p]=ni;
        }
    }
    #pragma unroll
    for(int p=0;p<4;p++){
        #pragma unroll
        for(int y=0;y<2;y++){
            s_red[sub*512 + (kxg*4+p)*16 + kyp*2 + y] = make_float2(aR[p][y], aI[p][y]);
        }
    }
    __syncthreads();
    #pragma unroll
    for(int u=0;u<2;u++){
        int oidx = t*2 + u;
        float xr=0.0f, xi=0.0f;
        #pragma unroll
        for(int q=0;q<4;q++){ float2 pr = s_red[q*512 + oidx]; xr += pr.x; xi += pr.y; }
        vftp[(size_t)blockIdx.x*512 + oidx] = make_float2(xr, xi);
    }
}

// mix + I1 fused. grid (b,o)=256 blocks, 256 thr. Sums 4 f2 partials.
__global__ __launch_bounds__(256) void fno_mixi1_k(const float2* __restrict__ vftp, const float2* __restrict__ Wt2,
                                                   float2* __restrict__ Gh, int l){
    __shared__ float2 s_oft[512];
    __shared__ float s_c[256], s_s[256];
    int t = threadIdx.x;
    build_tables(s_c, s_s);
    int b = blockIdx.x >> 4, o = blockIdx.x & 15;
    const float2* vb = vftp + (size_t)b*16*2048;
    const float2* wb = Wt2 + (size_t)(l*16 + o)*512*16;
    #pragma unroll
    for(int u=0;u<2;u++){
        int m = t + u*256;
        const float2* wm = wb + m*16;
        float aR=0.0f, aI=0.0f;
        #pragma unroll
        for(int i=0;i<16;i++){
            const float2* q0 = vb + i*2048 + m;
            float2 a0 = q0[0], a1 = q0[512], a2 = q0[1024], a3 = q0[1536];
            float vxr = a0.x+a1.x+a2.x+a3.x;
            float vxi = a0.y+a1.y+a2.y+a3.y;
            float2 wv = wm[i];
            aR += vxr*wv.x - vxi*wv.y;
            aI += vxr*wv.y + vxi*wv.x;
        }
        s_oft[m] = make_float2(aR, aI);
    }
    __syncthreads();
    int h = t;
    float hc = s_c[h], hs = s_s[h];
    float aR[16], aI[16];
    #pragma unroll
    for(int ky=0;ky<16;ky++){ aR[ky]=0.0f; aI[ky]=0.0f; }
    float rc = 1.0f, rs = 0.0f;        // e^{+i*0}
    for(int kxIdx=0;kxIdx<16;kxIdx++){
        #pragma unroll
        for(int ky=0;ky<16;ky++){
            float2 g = s_oft[kxIdx*16 + ky];
            aR[ky] += g.x*rc - g.y*rs;
            aI[ky] += g.x*rs + g.y*rc;
        }
        float nr = rc*hc - rs*hs, ni = rc*hs + rs*hc;
        rc=nr; rs=ni;
    }
    { int i0 = (240*h)&255; rc = s_c[i0]; rs = s_s[i0]; }   // restart at kx=240
    for(int kxIdx=16;kxIdx<32;kxIdx++){
        #pragma unroll
        for(int ky=0;ky<16;ky++){
            float2 g = s_oft[kxIdx*16 + ky];
            aR[ky] += g.x*rc - g.y*rs;
            aI[ky] += g.x*rs + g.y*rc;
        }
        float nr = rc*hc - rs*hs, ni = rc*hs + rs*hc;
        rc=nr; rs=ni;
    }
    const float inv = 1.0f/65536.0f;
    float4 pack[8];
    #pragma unroll
    for(int ky=0;ky<16;ky+=2){
        float s0 = (ky==0) ? inv : 2.0f*inv;
        float s1 = 2.0f*inv;
        pack[ky/2] = make_float4(aR[ky]*s0, aI[ky]*s0, aR[ky+1]*s1, aI[ky+1]*s1);
    }
    float4* d4 = (float4*)(Gh + ((size_t)(b*256 + h)*16 + o)*16);
    #pragma unroll
    for(int q=0;q<8;q++) d4[q] = pack[q];
}

// I2 + skip + bias (+gelu), in place on v; optional fused row DFT -> Fw.
__global__ __launch_bounds__(256) void fno_i2f1_k(const float2* __restrict__ Gh, float* __restrict__ v,
                                                  const float* __restrict__ skw, const float* __restrict__ skb,
                                                  float2* __restrict__ Fw, int l, int do_gelu, int do_f1){
    __shared__ float s_v[16*260];
    __shared__ float2 s_g[256];
    __shared__ float s_c[256], s_s[256];
    int t = threadIdx.x;
    build_tables(s_c, s_s);
    int b = blockIdx.x >> 8, h = blockIdx.x & 255;
    #pragma unroll
    for(int c=0;c<16;c++) s_v[c*260 + t] = v[((size_t)(b*16 + c)*256 + h)*256 + t];
    if(t < 128) ((float4*)s_g)[t] = ((const float4*)(Gh + (size_t)(b*256 + h)*256))[t];
    __syncthreads();
    float vr[16];
    #pragma unroll
    for(int c=0;c<16;c++) vr[c] = s_v[c*260 + t];
    float cw[16], sw[16];
    {
        int idx = 0;
        #pragma unroll
        for(int ky=0;ky<16;ky++){ cw[ky]=s_c[idx]; sw[ky]=s_s[idx]; idx = (idx + t)&255; }
    }
    const float* swl = skw + l*256;
    const float* sbl = skb + l*16;
    float outv[16];
    for(int o=0;o<16;o++){
        float acc = sbl[o];
        #pragma unroll
        for(int ky=0;ky<16;ky++){
            float2 gv = s_g[o*16 + ky];
            acc += gv.x*cw[ky] - gv.y*sw[ky];
        }
        const float* swo = swl + o*16;
        #pragma unroll
        for(int c=0;c<16;c++) acc += swo[c]*vr[c];
        if(do_gelu) acc = gelu_f(acc);
        outv[o] = acc;
    }
    __syncthreads();   // everyone done reading s_v columns before in-place overwrite
    #pragma unroll
    for(int o=0;o<16;o++){
        v[((size_t)(b*16 + o)*256 + h)*256 + t] = outv[o];
        s_v[o*260 + t] = outv[o];
    }
    if(do_f1){
        __syncthreads();
        int c = t >> 4, ky = t & 15;
        float2 r = dft_row(s_v + c*260, s_c, s_s, ky);
        Fw[((size_t)(b*16 + c)*256 + h)*16 + ky] = r;
    }
}

// projection: poolq[b][k] += sum_pixels gelu(b1 + W1 v).
// grid 2048 = (b, hp). Thread: row = hp*2 + (t>>7), pixels wp, wp+1 with wp = (t&127)*2.
// W1 + b1 staged in LDS; weight reads are b128 broadcasts. Chunked pool reduce (round-2 layout).
__global__ __launch_bounds__(256) void fno_proj3_k(const float* __restrict__ v, const float* __restrict__ W1,
                                                   const float* __restrict__ b1, float* __restrict__ poolq){
    __shared__ float4 s_q[256*9];      // 36 KB reduce buffer
    __shared__ float4 s_w[512];        // W1[k][c] as float4[k*4 + c4], 8 KB
    __shared__ float  s_b[128];
    int t = threadIdx.x;
    int b = blockIdx.x >> 7, hp = blockIdx.x & 127;
    int row = hp*2 + (t>>7);
    int wp  = (t & 127)*2;
    {
        const float4* w4 = (const float4*)W1;
        for(int i=t;i<512;i+=256) s_w[i] = w4[i];
        if(t < 128) s_b[t] = b1[t];
    }
    float vr[2][16];
    #pragma unroll
    for(int c=0;c<16;c++){
        float2 vv = *(const float2*)&v[((size_t)(b*16 + c)*256 + row)*256 + wp];
        vr[0][c] = vv.x; vr[1][c] = vv.y;
    }
    __syncthreads();
    int g8 = t & 7, pr = t >> 3;
    float4 acc[4];
    #pragma unroll
    for(int ch=0;ch<4;ch++) acc[ch] = make_float4(0,0,0,0);
    for(int ch=0; ch<4; ch++){
        #pragma unroll
        for(int kg=0; kg<8; kg++){
            int kb = ch*32 + kg*4;
            float u[2][4];
            #pragma unroll
            for(int p=0;p<2;p++){
                u[p][0]=s_b[kb]; u[p][1]=s_b[kb+1]; u[p][2]=s_b[kb+2]; u[p][3]=s_b[kb+3];
            }
            #pragma unroll
            for(int j=0;j<4;j++){
                const float4 wa = s_w[(kb+j)*4+0];
                const float4 wbv= s_w[(kb+j)*4+1];
                const float4 wc = s_w[(kb+j)*4+2];
                const float4 wd = s_w[(kb+j)*4+3];
                #pragma unroll
                for(int p=0;p<2;p++){
                    u[p][j] += vr[p][0]*wa.x + vr[p][1]*wa.y + vr[p][2]*wa.z + vr[p][3]*wa.w
                             + vr[p][4]*wbv.x + vr[p][5]*wbv.y + vr[p][6]*wbv.z + vr[p][7]*wbv.w
                             + vr[p][8]*wc.x + vr[p][9]*wc.y + vr[p][10]*wc.z + vr[p][11]*wc.w
                             + vr[p][12]*wd.x + vr[p][13]*wd.y + vr[p][14]*wd.z + vr[p][15]*wd.w;
                }
            }
            float4 valv;
            valv.x = gelu_f(u[0][0]) + gelu_f(u[1][0]);
            valv.y = gelu_f(u[0][1]) + gelu_f(u[1][1]);
            valv.z = gelu_f(u[0][2]) + gelu_f(u[1][2]);
            valv.w = gelu_f(u[0][3]) + gelu_f(u[1][3]);
            s_q[t*9 + kg] = valv;
        }
        __syncthreads();
        #pragma unroll
        for(int pp=0;pp<8;pp++){
            float4 f = s_q[(pr*8 + pp)*9 + g8];
            acc[ch].x += f.x; acc[ch].y += f.y; acc[ch].z += f.z; acc[ch].w += f.w;
        }
        __syncthreads();
    }
    #pragma unroll
    for(int ch=0;ch<4;ch++) s_q[(ch*8 + g8)*33 + pr] = acc[ch];
    __syncthreads();
    if(t < 32){
        float4 a = make_float4(0,0,0,0);
        for(int pr2=0;pr2<32;pr2++){
            float4 f = s_q[t*33 + pr2];
            a.x += f.x; a.y += f.y; a.z += f.z; a.w += f.w;
        }
        int kbase = (t>>3)*32 + (t&7)*4;
        atomicAdd(&poolq[b*128 + kbase + 0], a.x);
        atomicAdd(&poolq[b*128 + kbase + 1], a.y);
        atomicAdd(&poolq[b*128 + kbase + 2], a.z);
        atomicAdd(&poolq[b*128 + kbase + 3], a.w);
    }
}

// head: pooled = W2 * (poolq/65536) + b2 ; out = tanh(pooled @ head_w^T + head_b)
__global__ __launch_bounds__(1024) void fno_head_k(const float* __restrict__ poolq, const float* __restrict__ W2,
                                                   const float* __restrict__ b2, const float* __restrict__ hw,
                                                   const float* __restrict__ hb, float* __restrict__ out){
    __shared__ float s_pool[16][68];
    int t = threadIdx.x;
    int b = t >> 6, j = t & 63;
    const float* pq = poolq + b*128;
    const float* w2 = W2 + j*128;
    float dot = 0.0f;
    for(int k=0;k<128;k++) dot += w2[k]*pq[k];
    s_pool[b][j] = b2[j] + dot*(1.0f/65536.0f);
    __syncthreads();
    if(t < 32){
        int bb = t >> 1, c2 = t & 1;
        float z = hb[c2];
        #pragma unroll
        for(int j2=0;j2<64;j2++) z += hw[c2*64 + j2]*s_pool[bb][j2];
        out[bb*2 + c2] = tanhf(z);
    }
}

extern "C" void kernel_launch(void* const* d_in, const int* in_sizes, int n_in,
                              void* d_out, int out_size, void* d_ws, size_t ws_size,
                              hipStream_t stream) {
    const float* x       = (const float*)d_in[0];
    const float* lift_w  = (const float*)d_in[1];
    const float* lift_b  = (const float*)d_in[2];
    const float* w1r     = (const float*)d_in[3];
    const float* w1i     = (const float*)d_in[4];
    const float* w2r     = (const float*)d_in[5];
    const float* w2i     = (const float*)d_in[6];
    const float* skip_w  = (const float*)d_in[7];
    const float* skip_b  = (const float*)d_in[8];
    const float* proj_w1 = (const float*)d_in[9];
    const float* proj_b1 = (const float*)d_in[10];
    const float* proj_w2 = (const float*)d_in[11];
    const float* proj_b2 = (const float*)d_in[12];
    const float* head_w  = (const float*)d_in[13];
    const float* head_b  = (const float*)d_in[14];
    float* out = (float*)d_out;

    float*  v    = (float*)d_ws;                 // 16,777,216 floats
    float2* Fw   = (float2*)(v + 16777216);      // 1,048,576 float2
    float2* vftp = Fw  + 1048576;                // 524,288 float2 (256 bc x 4 q x 512)
    float2* Gh   = vftp + 524288;                // 1,048,576 float2
    float2* Wt2  = Gh  + 1048576;                // 524,288 float2
    float*  poolq = (float*)(Wt2 + 524288);      // 2,048 floats (total ~88 MB)

    fno_zero_k<<<8, 256, 0, stream>>>(poolq, 2048);
    fno_wprep_k<<<2048, 256, 0, stream>>>(w1r, w1i, w2r, w2i, Wt2);
    fno_liftf1_k<<<4096, 256, 0, stream>>>(x, lift_w, lift_b, v, Fw);

    for(int l=0; l<4; l++){
        fno_f2q_k<<<1024, 256, 0, stream>>>(Fw, vftp);
        fno_mixi1_k<<<256, 256, 0, stream>>>(vftp, Wt2, Gh, l);
        fno_i2f1_k<<<4096, 256, 0, stream>>>(Gh, v, skip_w, skip_b, Fw, l,
                                             (l<3)?1:0, (l<3)?1:0);
    }

    fno_proj3_k<<<2048, 256, 0, stream>>>(v, proj_w1, proj_b1, poolq);
    fno_head_k<<<1, 1024, 0, stream>>>(poolq, proj_w2, proj_b2, head_w, head_b, out);
}

// Round 4
// 612.389 us; speedup vs baseline: 1.1472x; 1.0831x over previous
//
#include <hip/hip_runtime.h>
#include <math.h>

// FNO with global head, MI355X. Round 4.
//   liftf1 : x -> v and Fw (row DFT fused with lift)
//   f2q    : Fw -> vftp (column DFT, quarter h-ranges)
//   mixi1  : vftp -> channel mix in LDS -> Gh
//   i2f1   : Gh + skip + bias (+gelu) -> v, fused row DFT -> Fw (l<3)
//   proj4  : v -> poolq ; 4 k/thread in regs, pixels streamed from LDS (b128)
//   head   : poolq -> out

#define TWO_PI_OVER_256 0.024543692606170259f

__device__ __forceinline__ float gelu_f(float x){
    // jax.nn.gelu approximate=True: 0.5x(1+tanh(z)) == x * sigmoid(2z)
    float x2 = x*x;
    float z2 = x*(1.5957691f + 0.07135482f*x2);   // 2*sqrt(2/pi)*(x + 0.044715 x^3)
    float e = __expf(-z2);
    return x * __builtin_amdgcn_rcpf(1.0f + e);   // v_rcp instead of precise div
}

__device__ __forceinline__ void build_tables(float* s_c, float* s_s){
    int t = threadIdx.x;
    if(t < 256){
        float ang = (float)t * TWO_PI_OVER_256;
        float sv, cv;
        sincosf(ang, &sv, &cv);
        s_c[t] = cv; s_s[t] = sv;
    }
}

// Row DFT: F(ky) = sum_w row[w] e^{-2pi i ky w/256}, j-split over w%4, rotator over w/4.
__device__ __forceinline__ float2 dft_row(const float* s_row, const float* s_c, const float* s_s, int ky){
    float stc = s_c[(4*ky)&255], sts = s_s[(4*ky)&255];
    float rc = 1.0f, rs = 0.0f;
    float accR[4] = {0,0,0,0}, accI[4] = {0,0,0,0};
    const float4* row4 = (const float4*)s_row;
    #pragma unroll 4
    for(int m=0;m<64;m++){
        float4 v4 = row4[m];
        accR[0]+=v4.x*rc; accI[0]+=v4.x*rs;
        accR[1]+=v4.y*rc; accI[1]+=v4.y*rs;
        accR[2]+=v4.z*rc; accI[2]+=v4.z*rs;
        accR[3]+=v4.w*rc; accI[3]+=v4.w*rs;
        float nr = rc*stc + rs*sts;
        float ni = rs*stc - rc*sts;
        rc=nr; rs=ni;
    }
    float oR=0.0f, oI=0.0f;
    #pragma unroll
    for(int j=0;j<4;j++){
        float cj = s_c[(ky*j)&255], sj = s_s[(ky*j)&255];
        oR += accR[j]*cj + accI[j]*sj;
        oI += accI[j]*cj - accR[j]*sj;
    }
    return make_float2(oR, oI);
}

__global__ __launch_bounds__(256) void fno_zero_k(float* __restrict__ p, int n){
    int i = blockIdx.x*256 + threadIdx.x;
    if(i < n) p[i] = 0.0f;
}

// Wt2[l][o][m=kx*16+ky][i] float2
__global__ __launch_bounds__(256) void fno_wprep_k(const float* __restrict__ w1r, const float* __restrict__ w1i,
                                                   const float* __restrict__ w2r, const float* __restrict__ w2i,
                                                   float2* __restrict__ Wt2){
    int lin = blockIdx.x;              // 4*16*32 = 2048 blocks: (l,o,kxIdx)
    int l  = lin >> 9;
    int rem = lin & 511;
    int o = rem >> 5;
    int kxIdx = rem & 31;
    int t = threadIdx.x;
    int ky = t >> 4, i = t & 15;
    int x = kxIdx & 15;
    const float* wr = (kxIdx < 16) ? w1r : w2r;
    const float* wi = (kxIdx < 16) ? w1i : w2i;
    int src = (((l*16 + i)*16 + o)*16 + x)*16 + ky;
    Wt2[((size_t)(l*16 + o)*512 + kxIdx*16 + ky)*16 + i] = make_float2(wr[src], wi[src]);
}

// lift + row DFT. grid 4096 (b,h), 256 thr.
__global__ __launch_bounds__(256) void fno_liftf1_k(const float* __restrict__ x, const float* __restrict__ lw,
                                                    const float* __restrict__ lb, float* __restrict__ v,
                                                    float2* __restrict__ Fw){
    __shared__ float s_v[16*260];
    __shared__ float s_c[256], s_s[256];
    int t = threadIdx.x;
    build_tables(s_c, s_s);
    int b = blockIdx.x >> 8, h = blockIdx.x & 255;
    float xv = x[(b*256 + h)*256 + t];
    #pragma unroll
    for(int c=0;c<16;c++){
        float val = lw[c]*xv + lb[c];
        v[((size_t)(b*16 + c)*256 + h)*256 + t] = val;
        s_v[c*260 + t] = val;
    }
    __syncthreads();
    int c = t >> 4, ky = t & 15;
    float2 r = dft_row(s_v + c*260, s_c, s_s, ky);
    Fw[((size_t)(b*16 + c)*256 + h)*16 + ky] = r;
}

// F2 quarter-split: vftp[(bc*4+qr)][oidx] = sum_{h in quarter} Fw[bc][h][ky] e^{-2pi i kx h/256}
__global__ __launch_bounds__(256) void fno_f2q_k(const float2* __restrict__ Fw, float2* __restrict__ vftp){
    __shared__ float2 s_fw[1024];      // 64 h x 16 ky
    __shared__ float2 s_red[2048];
    __shared__ float s_c[256], s_s[256];
    int t = threadIdx.x;
    build_tables(s_c, s_s);
    int bc = blockIdx.x >> 2, qr = blockIdx.x & 3;
    int qh = qr*64;
    {
        const float4* src = (const float4*)(Fw + (size_t)bc*4096 + qh*16);
        float4* d4 = (float4*)s_fw;
        for(int i=t;i<512;i+=256) d4[i] = src[i];
    }
    __syncthreads();
    int sub = t>>6, kyp = (t>>3)&7, kxg = t&7;
    int h0 = qh + sub*16;
    float rc[4], rs[4], stc[4], sts[4], aR[4][2], aI[4][2];
    #pragma unroll
    for(int p=0;p<4;p++){
        int kxIdx = kxg*4+p;
        int kx = kxIdx + ((kxIdx>=16)?224:0);
        int i0 = (kx*h0)&255;
        rc[p] = s_c[i0]; rs[p] = -s_s[i0];      // rot = e^{-i phi}
        stc[p] = s_c[kx]; sts[p] = s_s[kx];
        aR[p][0]=aR[p][1]=aI[p][0]=aI[p][1]=0.0f;
    }
    #pragma unroll 4
    for(int hh=0; hh<16; hh++){
        float4 f = *(const float4*)&s_fw[(sub*16 + hh)*16 + kyp*2];
        #pragma unroll
        for(int p=0;p<4;p++){
            aR[p][0] += f.x*rc[p] - f.y*rs[p];
            aI[p][0] += f.x*rs[p] + f.y*rc[p];
            aR[p][1] += f.z*rc[p] - f.w*rs[p];
            aI[p][1] += f.z*rs[p] + f.w*rc[p];
            float nr = rc[p]*stc[p] + rs[p]*sts[p];
            float ni = rs[p]*stc[p] - rc[p]*sts[p];
            rc[p]=nr; rs[p]=ni;
        }
    }
    #pragma unroll
    for(int p=0;p<4;p++){
        #pragma unroll
        for(int y=0;y<2;y++){
            s_red[sub*512 + (kxg*4+p)*16 + kyp*2 + y] = make_float2(aR[p][y], aI[p][y]);
        }
    }
    __syncthreads();
    #pragma unroll
    for(int u=0;u<2;u++){
        int oidx = t*2 + u;
        float xr=0.0f, xi=0.0f;
        #pragma unroll
        for(int q=0;q<4;q++){ float2 pr = s_red[q*512 + oidx]; xr += pr.x; xi += pr.y; }
        vftp[(size_t)blockIdx.x*512 + oidx] = make_float2(xr, xi);
    }
}

// mix + I1 fused. grid (b,o)=256 blocks, 256 thr. Sums 4 f2 partials.
__global__ __launch_bounds__(256) void fno_mixi1_k(const float2* __restrict__ vftp, const float2* __restrict__ Wt2,
                                                   float2* __restrict__ Gh, int l){
    __shared__ float2 s_oft[512];
    __shared__ float s_c[256], s_s[256];
    int t = threadIdx.x;
    build_tables(s_c, s_s);
    int b = blockIdx.x >> 4, o = blockIdx.x & 15;
    const float2* vb = vftp + (size_t)b*16*2048;
    const float2* wb = Wt2 + (size_t)(l*16 + o)*512*16;
    #pragma unroll
    for(int u=0;u<2;u++){
        int m = t + u*256;
        const float2* wm = wb + m*16;
        float aR=0.0f, aI=0.0f;
        #pragma unroll
        for(int i=0;i<16;i++){
            const float2* q0 = vb + i*2048 + m;
            float2 a0 = q0[0], a1 = q0[512], a2 = q0[1024], a3 = q0[1536];
            float vxr = a0.x+a1.x+a2.x+a3.x;
            float vxi = a0.y+a1.y+a2.y+a3.y;
            float2 wv = wm[i];
            aR += vxr*wv.x - vxi*wv.y;
            aI += vxr*wv.y + vxi*wv.x;
        }
        s_oft[m] = make_float2(aR, aI);
    }
    __syncthreads();
    int h = t;
    float hc = s_c[h], hs = s_s[h];
    float aR[16], aI[16];
    #pragma unroll
    for(int ky=0;ky<16;ky++){ aR[ky]=0.0f; aI[ky]=0.0f; }
    float rc = 1.0f, rs = 0.0f;        // e^{+i*0}
    for(int kxIdx=0;kxIdx<16;kxIdx++){
        #pragma unroll
        for(int ky=0;ky<16;ky++){
            float2 g = s_oft[kxIdx*16 + ky];
            aR[ky] += g.x*rc - g.y*rs;
            aI[ky] += g.x*rs + g.y*rc;
        }
        float nr = rc*hc - rs*hs, ni = rc*hs + rs*hc;
        rc=nr; rs=ni;
    }
    { int i0 = (240*h)&255; rc = s_c[i0]; rs = s_s[i0]; }   // restart at kx=240
    for(int kxIdx=16;kxIdx<32;kxIdx++){
        #pragma unroll
        for(int ky=0;ky<16;ky++){
            float2 g = s_oft[kxIdx*16 + ky];
            aR[ky] += g.x*rc - g.y*rs;
            aI[ky] += g.x*rs + g.y*rc;
        }
        float nr = rc*hc - rs*hs, ni = rc*hs + rs*hc;
        rc=nr; rs=ni;
    }
    const float inv = 1.0f/65536.0f;
    float4 pack[8];
    #pragma unroll
    for(int ky=0;ky<16;ky+=2){
        float s0 = (ky==0) ? inv : 2.0f*inv;
        float s1 = 2.0f*inv;
        pack[ky/2] = make_float4(aR[ky]*s0, aI[ky]*s0, aR[ky+1]*s1, aI[ky+1]*s1);
    }
    float4* d4 = (float4*)(Gh + ((size_t)(b*256 + h)*16 + o)*16);
    #pragma unroll
    for(int q=0;q<8;q++) d4[q] = pack[q];
}

// I2 + skip + bias (+gelu), in place on v; optional fused row DFT -> Fw.
__global__ __launch_bounds__(256) void fno_i2f1_k(const float2* __restrict__ Gh, float* __restrict__ v,
                                                  const float* __restrict__ skw, const float* __restrict__ skb,
                                                  float2* __restrict__ Fw, int l, int do_gelu, int do_f1){
    __shared__ float s_v[16*260];
    __shared__ float2 s_g[256];
    __shared__ float s_c[256], s_s[256];
    int t = threadIdx.x;
    build_tables(s_c, s_s);
    int b = blockIdx.x >> 8, h = blockIdx.x & 255;
    #pragma unroll
    for(int c=0;c<16;c++) s_v[c*260 + t] = v[((size_t)(b*16 + c)*256 + h)*256 + t];
    if(t < 128) ((float4*)s_g)[t] = ((const float4*)(Gh + (size_t)(b*256 + h)*256))[t];
    __syncthreads();
    float vr[16];
    #pragma unroll
    for(int c=0;c<16;c++) vr[c] = s_v[c*260 + t];
    float cw[16], sw[16];
    {
        int idx = 0;
        #pragma unroll
        for(int ky=0;ky<16;ky++){ cw[ky]=s_c[idx]; sw[ky]=s_s[idx]; idx = (idx + t)&255; }
    }
    const float* swl = skw + l*256;
    const float* sbl = skb + l*16;
    float outv[16];
    for(int o=0;o<16;o++){
        float acc = sbl[o];
        #pragma unroll
        for(int ky=0;ky<16;ky++){
            float2 gv = s_g[o*16 + ky];
            acc += gv.x*cw[ky] - gv.y*sw[ky];
        }
        const float* swo = swl + o*16;
        #pragma unroll
        for(int c=0;c<16;c++) acc += swo[c]*vr[c];
        if(do_gelu) acc = gelu_f(acc);
        outv[o] = acc;
    }
    __syncthreads();   // everyone done reading s_v columns before in-place overwrite
    #pragma unroll
    for(int o=0;o<16;o++){
        v[((size_t)(b*16 + o)*256 + h)*256 + t] = outv[o];
        s_v[o*260 + t] = outv[o];
    }
    if(do_f1){
        __syncthreads();
        int c = t >> 4, ky = t & 15;
        float2 r = dft_row(s_v + c*260, s_c, s_s, ky);
        Fw[((size_t)(b*16 + c)*256 + h)*16 + ky] = r;
    }
}

// projection: poolq[b][k] += sum_pixels gelu(b1 + W1 v).
// grid 1024 = (b, rg): block covers 4 rows. thread: kq = t&31 (4 k in regs), pg = t>>5 (32 px).
// Pixels streamed from LDS s_v[px*20 + c] via ds_read_b128 (2 distinct addrs/wave -> multicast).
__global__ __launch_bounds__(256) void fno_proj4_k(const float* __restrict__ v, const float* __restrict__ W1,
                                                   const float* __restrict__ b1, float* __restrict__ poolq){
    __shared__ float s_v[256*20];      // 20 KB, stride 20: 16B-aligned b128 per px
    __shared__ float s_red[128*9];
    int t = threadIdx.x;
    int b = blockIdx.x >> 6, rg = blockIdx.x & 63;
    int kq = t & 31, pg = t >> 5;
    float w[4][16], bias[4];
    #pragma unroll
    for(int j=0;j<4;j++){
        const float4* wr = (const float4*)(W1 + (kq*4 + j)*16);
        float4 a = wr[0], bb = wr[1], c = wr[2], d = wr[3];
        w[j][0]=a.x;  w[j][1]=a.y;  w[j][2]=a.z;  w[j][3]=a.w;
        w[j][4]=bb.x; w[j][5]=bb.y; w[j][6]=bb.z; w[j][7]=bb.w;
        w[j][8]=c.x;  w[j][9]=c.y;  w[j][10]=c.z; w[j][11]=c.w;
        w[j][12]=d.x; w[j][13]=d.y; w[j][14]=d.z; w[j][15]=d.w;
        bias[j] = b1[kq*4 + j];
    }
    float acc[4] = {0.0f, 0.0f, 0.0f, 0.0f};
    for(int r=0;r<4;r++){
        int row = rg*4 + r;
        __syncthreads();               // previous iteration's reads done
        #pragma unroll
        for(int c=0;c<16;c++) s_v[t*20 + c] = v[((size_t)(b*16 + c)*256 + row)*256 + t];
        __syncthreads();
        const float* base = s_v + pg*32*20;
        #pragma unroll 2
        for(int px=0;px<32;px++){
            const float4* vp = (const float4*)(base + px*20);
            float4 v0 = vp[0], v1 = vp[1], v2 = vp[2], v3 = vp[3];
            #pragma unroll
            for(int j=0;j<4;j++){
                float u = bias[j]
                    + v0.x*w[j][0]  + v0.y*w[j][1]  + v0.z*w[j][2]  + v0.w*w[j][3]
                    + v1.x*w[j][4]  + v1.y*w[j][5]  + v1.z*w[j][6]  + v1.w*w[j][7]
                    + v2.x*w[j][8]  + v2.y*w[j][9]  + v2.z*w[j][10] + v2.w*w[j][11]
                    + v3.x*w[j][12] + v3.y*w[j][13] + v3.z*w[j][14] + v3.w*w[j][15];
                acc[j] += gelu_f(u);
            }
        }
    }
    __syncthreads();
    #pragma unroll
    for(int j=0;j<4;j++) s_red[(kq*4 + j)*9 + pg] = acc[j];
    __syncthreads();
    if(t < 128){
        float s = 0.0f;
        #pragma unroll
        for(int p=0;p<8;p++) s += s_red[t*9 + p];
        atomicAdd(&poolq[b*128 + t], s);
    }
}

// head: pooled = W2 * (poolq/65536) + b2 ; out = tanh(pooled @ head_w^T + head_b)
__global__ __launch_bounds__(1024) void fno_head_k(const float* __restrict__ poolq, const float* __restrict__ W2,
                                                   const float* __restrict__ b2, const float* __restrict__ hw,
                                                   const float* __restrict__ hb, float* __restrict__ out){
    __shared__ float s_pool[16][68];
    int t = threadIdx.x;
    int b = t >> 6, j = t & 63;
    const float* pq = poolq + b*128;
    const float* w2 = W2 + j*128;
    float dot = 0.0f;
    for(int k=0;k<128;k++) dot += w2[k]*pq[k];
    s_pool[b][j] = b2[j] + dot*(1.0f/65536.0f);
    __syncthreads();
    if(t < 32){
        int bb = t >> 1, c2 = t & 1;
        float z = hb[c2];
        #pragma unroll
        for(int j2=0;j2<64;j2++) z += hw[c2*64 + j2]*s_pool[bb][j2];
        out[bb*2 + c2] = tanhf(z);
    }
}

extern "C" void kernel_launch(void* const* d_in, const int* in_sizes, int n_in,
                              void* d_out, int out_size, void* d_ws, size_t ws_size,
                              hipStream_t stream) {
    const float* x       = (const float*)d_in[0];
    const float* lift_w  = (const float*)d_in[1];
    const float* lift_b  = (const float*)d_in[2];
    const float* w1r     = (const float*)d_in[3];
    const float* w1i     = (const float*)d_in[4];
    const float* w2r     = (const float*)d_in[5];
    const float* w2i     = (const float*)d_in[6];
    const float* skip_w  = (const float*)d_in[7];
    const float* skip_b  = (const float*)d_in[8];
    const float* proj_w1 = (const float*)d_in[9];
    const float* proj_b1 = (const float*)d_in[10];
    const float* proj_w2 = (const float*)d_in[11];
    const float* proj_b2 = (const float*)d_in[12];
    const float* head_w  = (const float*)d_in[13];
    const float* head_b  = (const float*)d_in[14];
    float* out = (float*)d_out;

    float*  v    = (float*)d_ws;                 // 16,777,216 floats
    float2* Fw   = (float2*)(v + 16777216);      // 1,048,576 float2
    float2* vftp = Fw  + 1048576;                // 524,288 float2 (256 bc x 4 q x 512)
    float2* Gh   = vftp + 524288;                // 1,048,576 float2
    float2* Wt2  = Gh  + 1048576;                // 524,288 float2
    float*  poolq = (float*)(Wt2 + 524288);      // 2,048 floats (total ~88 MB)

    fno_zero_k<<<8, 256, 0, stream>>>(poolq, 2048);
    fno_wprep_k<<<2048, 256, 0, stream>>>(w1r, w1i, w2r, w2i, Wt2);
    fno_liftf1_k<<<4096, 256, 0, stream>>>(x, lift_w, lift_b, v, Fw);

    for(int l=0; l<4; l++){
        fno_f2q_k<<<1024, 256, 0, stream>>>(Fw, vftp);
        fno_mixi1_k<<<256, 256, 0, stream>>>(vftp, Wt2, Gh, l);
        fno_i2f1_k<<<4096, 256, 0, stream>>>(Gh, v, skip_w, skip_b, Fw, l,
                                             (l<3)?1:0, (l<3)?1:0);
    }

    fno_proj4_k<<<1024, 256, 0, stream>>>(v, proj_w1, proj_b1, poolq);
    fno_head_k<<<1, 1024, 0, stream>>>(poolq, proj_w2, proj_b2, head_w, head_b, out);
}